// Round 3
// baseline (132117.639 us; speedup 1.0000x reference)
//
#include <hip/hip_runtime.h>
#include <hip/hip_cooperative_groups.h>

namespace cg = cooperative_groups;

// problem dims
#define B_   64
#define T_   800
#define U_   64
#define N_   64
#define KMIX 10
#define H_   512
#define O_   121
#define C4_  2048   // 4*H

// grid layout: homogeneous-role blocks
#define NB_L0  64
#define NB_L1  64
#define NB_L2  64
#define NB_OUT 16
#define NB_ATT 4
#define NBLK  (NB_L0 + NB_L1 + NB_L2 + NB_OUT + NB_ATT)  // 212
#define NTHR  512
#define NITER (T_ + 3)  // pipeline: L0@i, ATT/L1@i-1, L2@i-2, OUT@i-3

struct Params {
  const float* strokes; const float* transcr;
  const float* W0; const float* b0;
  const float* bd;
  const float* W1; const float* b1;
  const float* W2; const float* b2;
  const float* bo;
  const float4* PR0; const float4* PW0w;
  const float4* PH1; const float4* PR1; const float4* PW1w;
  const float4* PH2; const float4* PR2; const float4* PW2w;
  const float4* PWo; const float4* PWd;
  float* h0r; float* h1r; float* h2r;   // rings [4][B][H]
  float* c0; float* c1; float* c2;      // [B][H]
  float* wr;                            // ring [4][B][N]
  float* kapr;                          // ring [2][B][KMIX]
  float* outp; float* attp;
};

__device__ __forceinline__ float sigf(float x) { return 1.0f / (1.0f + expf(-x)); }

// quantize a double onto the fp32 grid INCLUDING subnormals, round-half-even.
// (cannot rely on (float) cast for subnormals: kernel f32 denorm mode may flush)
__device__ __forceinline__ double f32q(double x) {
  double ax = fabs(x);
  if (ax >= 0x1p-126) return (double)(float)x;   // normal range: HW cast is exact RN
  return rint(x * 0x1p149) * 0x1p-149;           // subnormal grid in exact double arith
}

// z-GEMV core: 4 gate columns (g*512+uj) share one X stream.
// W packed k-interleaved: float4 idx = (k/4)*2048 + col  -> 4 consecutive k's.
__device__ __forceinline__ void dot4g(const float4* __restrict__ X,
                                      const float4* __restrict__ W,
                                      int k4, int uj, float acc[4]) {
  #pragma unroll 2
  for (int kk = 0; kk < k4; ++kk) {
    float4 xv = X[kk];
    #pragma unroll
    for (int g = 0; g < 4; ++g) {
      float4 wv = W[kk * C4_ + g * H_ + uj];
      acc[g] = fmaf(xv.x, wv.x, acc[g]);
      acc[g] = fmaf(xv.y, wv.y, acc[g]);
      acc[g] = fmaf(xv.z, wv.z, acc[g]);
      acc[g] = fmaf(xv.w, wv.w, acc[g]);
    }
  }
}

__device__ __forceinline__ float dot1(const float4* __restrict__ X,
                                      const float4* __restrict__ W,
                                      int k4, int stride) {
  float a = 0.0f;
  #pragma unroll 4
  for (int kk = 0; kk < k4; ++kk) {
    float4 xv = X[kk];
    float4 wv = W[kk * stride];
    a = fmaf(xv.x, wv.x, a); a = fmaf(xv.y, wv.y, a);
    a = fmaf(xv.z, wv.z, a); a = fmaf(xv.w, wv.w, a);
  }
  return a;
}

// repack row-major (K x C, leading dim ld) into k-interleaved float4 layout
__global__ void pack_k(const float* __restrict__ src, float* __restrict__ dst,
                       int K, int C, int ld) {
  int idx = blockIdx.x * 256 + threadIdx.x;
  if (idx >= K * C) return;
  int k = idx / C, c = idx - k * C;
  dst[(size_t)(k >> 2) * C * 4 + (size_t)c * 4 + (k & 3)] = src[(size_t)k * ld + c];
}

__global__ __launch_bounds__(NTHR, 1)
void net_kernel(Params p) {
  cg::grid_group grid = cg::this_grid();
  const int q = blockIdx.x;
  const int t = threadIdx.x;

  __shared__ float  s_y[16][32];   // y = exp(h0@Wd+bd): alpha 0..9, beta 10..19
  __shared__ float  s_k2[16][10];  // kappa2
  __shared__ double s_wf[16][66];  // wfull on the numpy-fp32 grid (held in double)

  for (int i = 0; i < NITER; ++i) {
    float acc[4] = {0.f, 0.f, 0.f, 0.f};
    int uj = 0, ub = 0;
    bool act = false;

    // ---------------- phase A ----------------
    if (q < NB_L0) {                                  // layer0 z, t = i
      act = (i < T_);
      if (act) {
        uj = q * 8 + (t & 7); ub = t >> 3;
        const float* xs = &p.strokes[(ub * T_ + i) * 3];
        float x0 = xs[0], x1 = xs[1], x2 = xs[2];
        #pragma unroll
        for (int g = 0; g < 4; ++g) {
          int col = g * H_ + uj;
          acc[g] = p.b0[col] + x0 * p.W0[col] + x1 * p.W0[C4_ + col] + x2 * p.W0[2 * C4_ + col];
        }
        const float4* X = (const float4*)&p.h0r[(size_t)((((i - 1) & 3)) * B_ + ub) * H_];
        dot4g(X, p.PR0, H_ / 4, uj, acc);
      }
    } else if (q < NB_L0 + NB_L1) {                   // layer1 z (minus w part), t = i-1
      act = (i >= 1 && i <= T_);
      if (act) {
        int tt = i - 1;
        uj = (q - NB_L0) * 8 + (t & 7); ub = t >> 3;
        const float* xs = &p.strokes[(ub * T_ + tt) * 3];
        float x0 = xs[0], x1 = xs[1], x2 = xs[2];
        #pragma unroll
        for (int g = 0; g < 4; ++g) {
          int col = g * H_ + uj;
          acc[g] = p.b1[col] + x0 * p.W1[576 * C4_ + col] + x1 * p.W1[577 * C4_ + col]
                             + x2 * p.W1[578 * C4_ + col];
        }
        const float4* Xh = (const float4*)&p.h0r[(size_t)((tt & 3) * B_ + ub) * H_];
        dot4g(Xh, p.PH1, H_ / 4, uj, acc);
        const float4* Xr = (const float4*)&p.h1r[(size_t)(((i - 2) & 3) * B_ + ub) * H_];
        dot4g(Xr, p.PR1, H_ / 4, uj, acc);
      }
    } else if (q < NB_L0 + NB_L1 + NB_L2) {           // layer2 z (complete), t = i-2
      act = (i >= 2 && i <= T_ + 1);
      if (act) {
        int tt = i - 2;
        uj = (q - NB_L0 - NB_L1) * 8 + (t & 7); ub = t >> 3;
        const float* xs = &p.strokes[(ub * T_ + tt) * 3];
        float x0 = xs[0], x1 = xs[1], x2 = xs[2];
        #pragma unroll
        for (int g = 0; g < 4; ++g) {
          int col = g * H_ + uj;
          acc[g] = p.b2[col] + x0 * p.W2[576 * C4_ + col] + x1 * p.W2[577 * C4_ + col]
                             + x2 * p.W2[578 * C4_ + col];
        }
        const float4* Xh = (const float4*)&p.h1r[(size_t)((tt & 3) * B_ + ub) * H_];
        dot4g(Xh, p.PH2, H_ / 4, uj, acc);
        const float4* Xw = (const float4*)&p.wr[(size_t)((tt & 3) * B_ + ub) * N_];
        dot4g(Xw, p.PW2w, N_ / 4, uj, acc);
        const float4* Xr = (const float4*)&p.h2r[(size_t)(((i - 3) & 3) * B_ + ub) * H_];
        dot4g(Xr, p.PR2, H_ / 4, uj, acc);
      }
    } else if (q < NB_L0 + NB_L1 + NB_L2 + NB_OUT) {  // output row, t = i-3
      act = (i >= 3 && i <= T_ + 2);
      if (act) {
        int tt = i - 3;
        int qo = q - NB_L0 - NB_L1 - NB_L2;
        int o0 = (qo * O_) / NB_OUT, o1 = ((qo + 1) * O_) / NB_OUT;
        int ol = t & 7; ub = t >> 3;
        if (ol < o1 - o0) {
          int oo = o0 + ol;
          int sl = tt & 3;
          const float4* X0 = (const float4*)&p.h0r[(size_t)(sl * B_ + ub) * H_];
          const float4* X1 = (const float4*)&p.h1r[(size_t)(sl * B_ + ub) * H_];
          const float4* X2 = (const float4*)&p.h2r[(size_t)(sl * B_ + ub) * H_];
          float a = p.bo[oo];
          a += dot1(X0, p.PWo + oo, 128, O_);
          a += dot1(X1, p.PWo + (size_t)128 * O_ + oo, 128, O_);
          a += dot1(X2, p.PWo + (size_t)256 * O_ + oo, 128, O_);
          p.outp[(size_t)(ub * T_ + tt) * O_ + oo] = a;  // clip is identity fwd
        }
      }
    } else {                                          // attention, t = i-1
      act = (i >= 1 && i <= T_);
      if (act) {
        int tt = i - 1;
        int qa = q - NB_L0 - NB_L1 - NB_L2 - NB_OUT;
        int lb = t >> 5, s = t & 31;
        ub = qa * 16 + lb;
        int sl = tt & 3;
        if (s < 30) {
          const float4* Xh = (const float4*)&p.h0r[(size_t)(sl * B_ + ub) * H_];
          float a = p.bd[s] + dot1(Xh, p.PWd + s, 128, 30);
          float y = expf(a);
          s_y[lb][s] = y;
          if (s >= 20) {  // dk columns -> kappa update; old slot parity (i-2)&1 == i&1
            float k2 = p.kapr[(size_t)(i & 1) * B_ * KMIX + ub * KMIX + (s - 20)] + y;
            p.kapr[(size_t)((i - 1) & 1) * B_ * KMIX + ub * KMIX + (s - 20)] = k2;
            s_k2[lb][s - 20] = k2;
          }
        }
        __syncthreads();
        // Emulate the np reference's float32 pipeline exactly at the underflow
        // boundary (it decides when att drops 64 -> 0):
        //   * argument chain in discrete fp32 ops (no fma contraction),
        //   * numpy SIMD float32 exp: NO gradual underflow -> exact 0 below
        //     FLT_MIN (this killed rounds 1 & 2: ocml expf makes subnormals
        //     down to e^-103.97, fp64 down to e^-745; np dies at e^-87.336),
        //   * alpha*e product rounded onto the fp32 (sub)normal grid,
        //   * exact (fp64) accumulation of those grid values.
        for (int u = s; u < U_ + 1; u += 32) {
          double wf = 0.0;
          #pragma unroll
          for (int k = 0; k < KMIX; ++k) {
            float d32 = s_k2[lb][k] - (float)(u + 1);
            float sq  = d32 * d32;
            float m   = -(s_y[lb][10 + k] * sq);
            double e  = exp((double)m);
            double e32 = (e < 0x1p-126) ? 0.0 : (double)(float)e;
            wf += f32q((double)s_y[lb][k] * e32);
          }
          s_wf[lb][u] = wf;
        }
        __syncthreads();
        if (s == 0) {  // argmax over 65, first-max wins (strict >)
          int am = 0; double bv = s_wf[lb][0];
          for (int u = 1; u < U_ + 1; ++u) {
            double v = s_wf[lb][u];
            if (v > bv) { bv = v; am = u; }
          }
          p.attp[ub * T_ + tt] = (float)am;
        }
        for (int n = s; n < N_; n += 32) {  // w2 = wfull[:,:U] @ transcriptions[b]
          float a2 = 0.f;
          for (int u = 0; u < U_; ++u)
            a2 = fmaf((float)s_wf[lb][u], p.transcr[(size_t)(ub * U_ + u) * N_ + n], a2);
          p.wr[(size_t)(sl * B_ + ub) * N_ + n] = a2;
        }
      }
    }

    grid.sync();

    // ---------------- phase B (w-dependent adds + LSTM pointwise) ----------------
    if (q < NB_L0) {
      if (act) {
        const float4* Xw = (const float4*)&p.wr[(size_t)(((i - 1) & 3) * B_ + ub) * N_];
        dot4g(Xw, p.PW0w, N_ / 4, uj, acc);
        int idx = ub * H_ + uj;
        float cn = sigf(acc[1]) * p.c0[idx] + sigf(acc[0]) * tanhf(acc[2]);
        float hn = sigf(acc[3]) * tanhf(cn);
        p.c0[idx] = cn;
        p.h0r[(size_t)((i & 3) * B_ + ub) * H_ + uj] = hn;
      }
    } else if (q < NB_L0 + NB_L1) {
      if (act) {
        int tt = i - 1;
        const float4* Xw = (const float4*)&p.wr[(size_t)((tt & 3) * B_ + ub) * N_];
        dot4g(Xw, p.PW1w, N_ / 4, uj, acc);
        int idx = ub * H_ + uj;
        float cn = sigf(acc[1]) * p.c1[idx] + sigf(acc[0]) * tanhf(acc[2]);
        float hn = sigf(acc[3]) * tanhf(cn);
        p.c1[idx] = cn;
        p.h1r[(size_t)((tt & 3) * B_ + ub) * H_ + uj] = hn;
      }
    } else if (q < NB_L0 + NB_L1 + NB_L2) {
      if (act) {
        int tt = i - 2;
        int idx = ub * H_ + uj;
        float cn = sigf(acc[1]) * p.c2[idx] + sigf(acc[0]) * tanhf(acc[2]);
        float hn = sigf(acc[3]) * tanhf(cn);
        p.c2[idx] = cn;
        p.h2r[(size_t)((tt & 3) * B_ + ub) * H_ + uj] = hn;
      }
    }

    grid.sync();
  }
}

extern "C" void kernel_launch(void* const* d_in, const int* in_sizes, int n_in,
                              void* d_out, int out_size, void* d_ws, size_t ws_size,
                              hipStream_t stream) {
  (void)in_sizes; (void)n_in; (void)out_size; (void)ws_size;
  const float* strokes = (const float*)d_in[0];
  const float* transcr = (const float*)d_in[1];
  const float* W0 = (const float*)d_in[2];
  const float* R0 = (const float*)d_in[3];
  const float* b0 = (const float*)d_in[4];
  const float* Wd = (const float*)d_in[5];
  const float* bd = (const float*)d_in[6];
  const float* W1 = (const float*)d_in[7];
  const float* R1 = (const float*)d_in[8];
  const float* b1 = (const float*)d_in[9];
  const float* W2 = (const float*)d_in[10];
  const float* R2 = (const float*)d_in[11];
  const float* b2 = (const float*)d_in[12];
  const float* Wo = (const float*)d_in[13];
  const float* bo = (const float*)d_in[14];

  float* ws = (float*)d_ws;
  size_t off = 0;
  float* h0r = ws + off; off += (size_t)4 * B_ * H_;
  float* h1r = ws + off; off += (size_t)4 * B_ * H_;
  float* h2r = ws + off; off += (size_t)4 * B_ * H_;
  float* c0  = ws + off; off += (size_t)B_ * H_;
  float* c1  = ws + off; off += (size_t)B_ * H_;
  float* c2  = ws + off; off += (size_t)B_ * H_;
  float* wr   = ws + off; off += (size_t)4 * B_ * N_;
  float* kapr = ws + off; off += (size_t)2 * B_ * KMIX;
  size_t stateFloats = off;
  float* PR0  = ws + off; off += (size_t)512 * 2048;
  float* PW0w = ws + off; off += (size_t)64 * 2048;
  float* PH1  = ws + off; off += (size_t)512 * 2048;
  float* PR1  = ws + off; off += (size_t)512 * 2048;
  float* PW1w = ws + off; off += (size_t)64 * 2048;
  float* PH2  = ws + off; off += (size_t)512 * 2048;
  float* PR2  = ws + off; off += (size_t)512 * 2048;
  float* PW2w = ws + off; off += (size_t)64 * 2048;
  float* PWo  = ws + off; off += (size_t)1536 * 121;
  float* PWd  = ws + off; off += (size_t)512 * 30;

  // zero recurrent state (ws is poisoned 0xAA before every call)
  hipMemsetAsync(d_ws, 0, stateFloats * sizeof(float), stream);

  auto packl = [&](const float* src, float* dst, int K, int C, int ld) {
    int n = K * C;
    pack_k<<<dim3((n + 255) / 256), dim3(256), 0, stream>>>(src, dst, K, C, ld);
  };
  packl(R0, PR0, 512, 2048, 2048);
  packl(W0 + 3 * 2048, PW0w, 64, 2048, 2048);
  packl(W1, PH1, 512, 2048, 2048);
  packl(R1, PR1, 512, 2048, 2048);
  packl(W1 + 512 * 2048, PW1w, 64, 2048, 2048);
  packl(W2, PH2, 512, 2048, 2048);
  packl(R2, PR2, 512, 2048, 2048);
  packl(W2 + 512 * 2048, PW2w, 64, 2048, 2048);
  packl(Wo, PWo, 1536, 121, 121);
  packl(Wd, PWd, 512, 30, 30);

  Params p;
  p.strokes = strokes; p.transcr = transcr;
  p.W0 = W0; p.b0 = b0; p.bd = bd;
  p.W1 = W1; p.b1 = b1; p.W2 = W2; p.b2 = b2; p.bo = bo;
  p.PR0 = (const float4*)PR0; p.PW0w = (const float4*)PW0w;
  p.PH1 = (const float4*)PH1; p.PR1 = (const float4*)PR1; p.PW1w = (const float4*)PW1w;
  p.PH2 = (const float4*)PH2; p.PR2 = (const float4*)PR2; p.PW2w = (const float4*)PW2w;
  p.PWo = (const float4*)PWo; p.PWd = (const float4*)PWd;
  p.h0r = h0r; p.h1r = h1r; p.h2r = h2r;
  p.c0 = c0; p.c1 = c1; p.c2 = c2;
  p.wr = wr; p.kapr = kapr;
  p.outp = (float*)d_out;
  p.attp = (float*)d_out + (size_t)B_ * T_ * O_;

  void* args[] = { (void*)&p };
  hipLaunchCooperativeKernel((const void*)net_kernel, dim3(NBLK), dim3(NTHR),
                             args, 0, stream);
}